// Round 1
// baseline (510.939 us; speedup 1.0000x reference)
//
#include <hip/hip_runtime.h>
#include <hip/hip_bf16.h>
#include <stdint.h>

typedef __bf16 bf16x8_t __attribute__((ext_vector_type(8)));
typedef float  f32x4_t  __attribute__((ext_vector_type(4)));

__device__ __forceinline__ float bf2f(unsigned int s) {
  unsigned int u = s << 16;
  float f; __builtin_memcpy(&f, &u, 4); return f;
}
__device__ __forceinline__ unsigned short f2bf(float f) {
  __hip_bfloat16 b = __float2bfloat16(f);
  unsigned short s; __builtin_memcpy(&s, &b, 2); return s;
}

// ---------------- weight absmean: two-stage deterministic reduction ----------------
__global__ void k_reduce_abs(const float* __restrict__ w, long n4, float* __restrict__ partials) {
  const float4* wv = (const float4*)w;
  float s = 0.0f;
  long stride = (long)gridDim.x * blockDim.x;
  for (long i = (long)blockIdx.x * blockDim.x + threadIdx.x; i < n4; i += stride) {
    float4 v = wv[i];
    s += fabsf(v.x) + fabsf(v.y) + fabsf(v.z) + fabsf(v.w);
  }
  #pragma unroll
  for (int off = 32; off; off >>= 1) s += __shfl_down(s, off);
  __shared__ float sw[4];
  if ((threadIdx.x & 63) == 0) sw[threadIdx.x >> 6] = s;
  __syncthreads();
  if (threadIdx.x == 0) partials[blockIdx.x] = sw[0] + sw[1] + sw[2] + sw[3];
}

__global__ void k_finalize_scales(const float* __restrict__ p1, const float* __restrict__ p2,
                                  float* __restrict__ scales, float inv1, float inv2) {
  int t = threadIdx.x;  // 256 threads
  float s1 = p1[t], s2 = p2[t];
  #pragma unroll
  for (int off = 32; off; off >>= 1) { s1 += __shfl_down(s1, off); s2 += __shfl_down(s2, off); }
  __shared__ float a1[4], a2[4];
  if ((t & 63) == 0) { a1[t >> 6] = s1; a2[t >> 6] = s2; }
  __syncthreads();
  if (t == 0) {
    scales[0] = fmaxf((a1[0]+a1[1]+a1[2]+a1[3]) * inv1, 1e-5f);  // dequant factor = clip(mean|w|,1e-5)
    scales[1] = fmaxf((a2[0]+a2[1]+a2[2]+a2[3]) * inv2, 1e-5f);
  }
}

// ---------------- ternary weight quant -> bf16 {-1,0,1} ----------------
__global__ void k_quant_w(const float* __restrict__ w, __hip_bfloat16* __restrict__ wq,
                          long n4, const float* __restrict__ scales, int which) {
  float s = 1.0f / scales[which];
  const float4* wv = (const float4*)w;
  ushort4* qv = (ushort4*)wq;
  long stride = (long)gridDim.x * blockDim.x;
  for (long i = (long)blockIdx.x * blockDim.x + threadIdx.x; i < n4; i += stride) {
    float4 v = wv[i];
    ushort4 o;
    o.x = f2bf(fminf(fmaxf(rintf(v.x * s), -1.0f), 1.0f));
    o.y = f2bf(fminf(fmaxf(rintf(v.y * s), -1.0f), 1.0f));
    o.z = f2bf(fminf(fmaxf(rintf(v.z * s), -1.0f), 1.0f));
    o.w = f2bf(fminf(fmaxf(rintf(v.w * s), -1.0f), 1.0f));
    qv[i] = o;
  }
}

// ---------------- rmsnorm + per-token absmax int8 fake-quant of x (D=1024) ----------------
__global__ void k_actq_x(const float* __restrict__ x, __hip_bfloat16* __restrict__ xq,
                         float* __restrict__ alpha) {
  const int D = 1024;
  size_t t = blockIdx.x;
  int tid = threadIdx.x;  // 256 threads * 4 elems
  const float4* row = (const float4*)(x + t * (size_t)D);
  float4 v = row[tid];
  float ss = v.x*v.x + v.y*v.y + v.z*v.z + v.w*v.w;
  float am = fmaxf(fmaxf(fabsf(v.x), fabsf(v.y)), fmaxf(fabsf(v.z), fabsf(v.w)));
  #pragma unroll
  for (int off = 32; off; off >>= 1) {
    ss += __shfl_down(ss, off);
    am = fmaxf(am, __shfl_down(am, off));
  }
  __shared__ float s_ss[4], s_am[4];
  if ((tid & 63) == 0) { s_ss[tid >> 6] = ss; s_am[tid >> 6] = am; }
  __syncthreads();
  ss = s_ss[0] + s_ss[1] + s_ss[2] + s_ss[3];
  am = fmaxf(fmaxf(s_am[0], s_am[1]), fmaxf(s_am[2], s_am[3]));
  float rms = rsqrtf(ss * (1.0f / D) + 1e-5f);
  float a   = fmaxf(am * rms, 1e-5f);
  float qs  = 127.0f / a;
  if (tid == 0) alpha[t] = a * (1.0f / 127.0f);
  ushort4 o;
  o.x = f2bf(fminf(fmaxf(rintf((v.x * rms) * qs), -128.0f), 127.0f));
  o.y = f2bf(fminf(fmaxf(rintf((v.y * rms) * qs), -128.0f), 127.0f));
  o.z = f2bf(fminf(fmaxf(rintf((v.z * rms) * qs), -128.0f), 127.0f));
  o.w = f2bf(fminf(fmaxf(rintf((v.w * rms) * qs), -128.0f), 127.0f));
  ((ushort4*)(xq + t * (size_t)D))[tid] = o;
}

// ---------------- rmsnorm + quant of h, in place (F=4096, bf16) ----------------
__global__ void k_actq_h(__hip_bfloat16* __restrict__ h, float* __restrict__ alpha) {
  const int F = 4096;
  size_t t = blockIdx.x;
  int tid = threadIdx.x;  // 256 threads * 16 elems
  uint4* row = (uint4*)(h + t * (size_t)F);
  uint4 u0 = row[tid], u1 = row[tid + 256];
  unsigned int uu[8] = {u0.x, u0.y, u0.z, u0.w, u1.x, u1.y, u1.z, u1.w};
  float f[16];
  #pragma unroll
  for (int i = 0; i < 8; i++) {
    f[2*i]   = bf2f(uu[i] & 0xffffu);
    f[2*i+1] = bf2f(uu[i] >> 16);
  }
  float ss = 0.0f, am = 0.0f;
  #pragma unroll
  for (int i = 0; i < 16; i++) { ss += f[i] * f[i]; am = fmaxf(am, fabsf(f[i])); }
  #pragma unroll
  for (int off = 32; off; off >>= 1) {
    ss += __shfl_down(ss, off);
    am = fmaxf(am, __shfl_down(am, off));
  }
  __shared__ float s_ss[4], s_am[4];
  if ((tid & 63) == 0) { s_ss[tid >> 6] = ss; s_am[tid >> 6] = am; }
  __syncthreads();
  ss = s_ss[0] + s_ss[1] + s_ss[2] + s_ss[3];
  am = fmaxf(fmaxf(s_am[0], s_am[1]), fmaxf(s_am[2], s_am[3]));
  float rms = rsqrtf(ss * (1.0f / F) + 1e-5f);
  float a   = fmaxf(am * rms, 1e-5f);
  float qs  = 127.0f / a;
  if (tid == 0) alpha[t] = a * (1.0f / 127.0f);
  unsigned int ou[8];
  #pragma unroll
  for (int i = 0; i < 8; i++) {
    unsigned short lo = f2bf(fminf(fmaxf(rintf((f[2*i]   * rms) * qs), -128.0f), 127.0f));
    unsigned short hi = f2bf(fminf(fmaxf(rintf((f[2*i+1] * rms) * qs), -128.0f), 127.0f));
    ou[i] = ((unsigned int)hi << 16) | (unsigned int)lo;
  }
  row[tid]       = make_uint4(ou[0], ou[1], ou[2], ou[3]);
  row[tid + 256] = make_uint4(ou[4], ou[5], ou[6], ou[7]);
}

// ---------------- MFMA GEMM: C[m,n] = sum_k A[m,k]*B[n,k]; fused scale/bias epilogue ----------------
// EPI==0: h = gelu(acc*alpha[m]*wdq + bias[n]) -> bf16   EPI==1: out = acc*alpha[m]*wdq + bias[n] -> f32
#define GLD16(GP, LP) __builtin_amdgcn_global_load_lds( \
    (__attribute__((address_space(1))) void*)(GP), \
    (__attribute__((address_space(3))) void*)(LP), 16, 0, 0)

template<int EPI>
__global__ __launch_bounds__(256) void k_gemm_bt(
    const __hip_bfloat16* __restrict__ A, const __hip_bfloat16* __restrict__ B,
    const float* __restrict__ bias, const float* __restrict__ alpha,
    const float* __restrict__ scales, int which,
    void* __restrict__ Cout, int M, int N, int K)
{
  __shared__ __align__(16) __hip_bfloat16 lA[128 * 32];
  __shared__ __align__(16) __hip_bfloat16 lB[128 * 32];
  int tid = threadIdx.x;
  int m0 = blockIdx.y * 128, n0 = blockIdx.x * 128;
  int lane = tid & 63, wid = tid >> 6;
  int wm = (wid >> 1) * 64, wn = (wid & 1) * 64;
  int lr = lane & 15, lk = lane >> 4;
  // staging: thread tid loads 16B; LDS linear layout [row][32] bf16, byte off = tid*16 per instr
  int rr_ = tid >> 2, c8 = (tid & 3) * 8;
  const __hip_bfloat16* ga0 = A + (size_t)(m0 + rr_) * K + c8;
  const __hip_bfloat16* ga1 = A + (size_t)(m0 + 64 + rr_) * K + c8;
  const __hip_bfloat16* gb0 = B + (size_t)(n0 + rr_) * K + c8;
  const __hip_bfloat16* gb1 = B + (size_t)(n0 + 64 + rr_) * K + c8;
  __hip_bfloat16* la0 = &lA[rr_ * 32 + c8];
  __hip_bfloat16* la1 = &lA[(64 + rr_) * 32 + c8];
  __hip_bfloat16* lb0 = &lB[rr_ * 32 + c8];
  __hip_bfloat16* lb1 = &lB[(64 + rr_) * 32 + c8];

  f32x4_t acc[4][4] = {};
  for (int kt = 0; kt < K; kt += 32) {
    GLD16(ga0, la0); GLD16(ga1, la1);
    GLD16(gb0, lb0); GLD16(gb1, lb1);
    ga0 += 32; ga1 += 32; gb0 += 32; gb1 += 32;
    __syncthreads();   // drains vmcnt -> LDS tiles ready
    bf16x8_t af[4], bfv[4];
    #pragma unroll
    for (int i = 0; i < 4; i++)
      af[i] = *reinterpret_cast<const bf16x8_t*>(&lA[(wm + i * 16 + lr) * 32 + lk * 8]);
    #pragma unroll
    for (int i = 0; i < 4; i++)
      bfv[i] = *reinterpret_cast<const bf16x8_t*>(&lB[(wn + i * 16 + lr) * 32 + lk * 8]);
    #pragma unroll
    for (int mi = 0; mi < 4; mi++)
      #pragma unroll
      for (int ni = 0; ni < 4; ni++)
        acc[mi][ni] = __builtin_amdgcn_mfma_f32_16x16x32_bf16(af[mi], bfv[ni], acc[mi][ni], 0, 0, 0);
    __syncthreads();   // compute done before next-tile overwrite
  }

  float wdq = scales[which];
  #pragma unroll
  for (int mi = 0; mi < 4; mi++) {
    int rowb = m0 + wm + mi * 16 + lk * 4;   // C row = (lane>>4)*4 + reg
    float al[4];
    #pragma unroll
    for (int q = 0; q < 4; q++) al[q] = alpha[rowb + q] * wdq;
    #pragma unroll
    for (int ni = 0; ni < 4; ni++) {
      int col = n0 + wn + ni * 16 + lr;      // C col = lane&15
      float bb = bias[col];
      #pragma unroll
      for (int q = 0; q < 4; q++) {
        float v = acc[mi][ni][q] * al[q] + bb;
        if constexpr (EPI == 0) {
          v = 0.5f * v * (1.0f + erff(v * 0.70710678118654752f));
          ((__hip_bfloat16*)Cout)[(size_t)(rowb + q) * N + col] = __float2bfloat16(v);
        } else {
          ((float*)Cout)[(size_t)(rowb + q) * N + col] = v;
        }
      }
    }
  }
}

extern "C" void kernel_launch(void* const* d_in, const int* in_sizes, int n_in,
                              void* d_out, int out_size, void* d_ws, size_t ws_size,
                              hipStream_t stream) {
  const float* x  = (const float*)d_in[0];
  const float* w1 = (const float*)d_in[1];
  const float* b1 = (const float*)d_in[2];
  const float* w2 = (const float*)d_in[3];
  const float* b2 = (const float*)d_in[4];
  const int  F = in_sizes[2];                 // 4096
  const int  D = in_sizes[4];                 // 1024
  const long T = (long)in_sizes[0] / D;       // 16384 tokens
  const long nW = (long)F * D;                // elements per weight matrix

  char* ws = (char*)d_ws;
  float* partials1 = (float*)ws;              // [256]
  float* partials2 = partials1 + 256;         // [256]
  float* scales    = partials2 + 256;         // [2] = {mean|w1| clip, mean|w2| clip}
  float* alpha1    = (float*)(ws + 4096);     // [T]
  float* alpha2    = alpha1 + T;              // [T]
  size_t off = 4096 + 2 * (size_t)T * sizeof(float);
  off = (off + 255) & ~(size_t)255;
  __hip_bfloat16* w1q = (__hip_bfloat16*)(ws + off); off += (size_t)nW * 2;
  __hip_bfloat16* w2q = (__hip_bfloat16*)(ws + off); off += (size_t)nW * 2;
  __hip_bfloat16* xq  = (__hip_bfloat16*)(ws + off); off += (size_t)T * D * 2;
  __hip_bfloat16* h   = (__hip_bfloat16*)(ws + off); off += (size_t)T * F * 2;
  if (ws_size < off) return;  // workspace too small; bail (output stays poisoned -> visible failure)

  float invW = (float)(1.0 / (double)nW);
  k_reduce_abs<<<256, 256, 0, stream>>>(w1, nW / 4, partials1);
  k_reduce_abs<<<256, 256, 0, stream>>>(w2, nW / 4, partials2);
  k_finalize_scales<<<1, 256, 0, stream>>>(partials1, partials2, scales, invW, invW);
  k_quant_w<<<2048, 256, 0, stream>>>(w1, w1q, nW / 4, scales, 0);
  k_quant_w<<<2048, 256, 0, stream>>>(w2, w2q, nW / 4, scales, 1);
  k_actq_x<<<(unsigned)T, 256, 0, stream>>>(x, xq, alpha1);

  dim3 g1((unsigned)(F / 128), (unsigned)(T / 128));
  k_gemm_bt<0><<<g1, 256, 0, stream>>>(xq, w1q, b1, alpha1, scales, 0, h, (int)T, F, D);

  k_actq_h<<<(unsigned)T, 256, 0, stream>>>(h, alpha2);

  dim3 g2((unsigned)(D / 128), (unsigned)(T / 128));
  k_gemm_bt<1><<<g2, 256, 0, stream>>>(h, w2q, b2, alpha2, scales, 1, d_out, (int)T, D, F);
}

// Round 2
// 452.332 us; speedup vs baseline: 1.1296x; 1.1296x over previous
//
#include <hip/hip_runtime.h>
#include <hip/hip_bf16.h>
#include <stdint.h>

typedef __bf16 bf16x8_t __attribute__((ext_vector_type(8)));
typedef float  f32x4_t  __attribute__((ext_vector_type(4)));

__device__ __forceinline__ float bf2f(unsigned int s) {
  unsigned int u = s << 16;
  float f; __builtin_memcpy(&f, &u, 4); return f;
}
__device__ __forceinline__ unsigned short f2bf(float f) {
  __hip_bfloat16 b = __float2bfloat16(f);
  unsigned short s; __builtin_memcpy(&s, &b, 2); return s;
}

// ---------------- weight absmean: two-stage deterministic reduction ----------------
__global__ void k_reduce_abs(const float* __restrict__ w, long n4, float* __restrict__ partials) {
  const float4* wv = (const float4*)w;
  float s = 0.0f;
  long stride = (long)gridDim.x * blockDim.x;
  for (long i = (long)blockIdx.x * blockDim.x + threadIdx.x; i < n4; i += stride) {
    float4 v = wv[i];
    s += fabsf(v.x) + fabsf(v.y) + fabsf(v.z) + fabsf(v.w);
  }
  #pragma unroll
  for (int off = 32; off; off >>= 1) s += __shfl_down(s, off);
  __shared__ float sw[4];
  if ((threadIdx.x & 63) == 0) sw[threadIdx.x >> 6] = s;
  __syncthreads();
  if (threadIdx.x == 0) partials[blockIdx.x] = sw[0] + sw[1] + sw[2] + sw[3];
}

__global__ void k_finalize_scales(const float* __restrict__ p1, const float* __restrict__ p2,
                                  float* __restrict__ scales, float inv1, float inv2) {
  int t = threadIdx.x;  // 256 threads
  float s1 = p1[t], s2 = p2[t];
  #pragma unroll
  for (int off = 32; off; off >>= 1) { s1 += __shfl_down(s1, off); s2 += __shfl_down(s2, off); }
  __shared__ float a1[4], a2[4];
  if ((t & 63) == 0) { a1[t >> 6] = s1; a2[t >> 6] = s2; }
  __syncthreads();
  if (t == 0) {
    scales[0] = fmaxf((a1[0]+a1[1]+a1[2]+a1[3]) * inv1, 1e-5f);
    scales[1] = fmaxf((a2[0]+a2[1]+a2[2]+a2[3]) * inv2, 1e-5f);
  }
}

// ---------------- ternary weight quant -> bf16 {-1,0,1} ----------------
__global__ void k_quant_w(const float* __restrict__ w, __hip_bfloat16* __restrict__ wq,
                          long n4, const float* __restrict__ scales, int which) {
  float s = 1.0f / scales[which];
  const float4* wv = (const float4*)w;
  ushort4* qv = (ushort4*)wq;
  long stride = (long)gridDim.x * blockDim.x;
  for (long i = (long)blockIdx.x * blockDim.x + threadIdx.x; i < n4; i += stride) {
    float4 v = wv[i];
    ushort4 o;
    o.x = f2bf(fminf(fmaxf(rintf(v.x * s), -1.0f), 1.0f));
    o.y = f2bf(fminf(fmaxf(rintf(v.y * s), -1.0f), 1.0f));
    o.z = f2bf(fminf(fmaxf(rintf(v.z * s), -1.0f), 1.0f));
    o.w = f2bf(fminf(fmaxf(rintf(v.w * s), -1.0f), 1.0f));
    qv[i] = o;
  }
}

// ---------------- rmsnorm + per-token absmax int8 fake-quant of x (D=1024) ----------------
__global__ void k_actq_x(const float* __restrict__ x, __hip_bfloat16* __restrict__ xq,
                         float* __restrict__ alpha) {
  const int D = 1024;
  size_t t = blockIdx.x;
  int tid = threadIdx.x;  // 256 threads * 4 elems
  const float4* row = (const float4*)(x + t * (size_t)D);
  float4 v = row[tid];
  float ss = v.x*v.x + v.y*v.y + v.z*v.z + v.w*v.w;
  float am = fmaxf(fmaxf(fabsf(v.x), fabsf(v.y)), fmaxf(fabsf(v.z), fabsf(v.w)));
  #pragma unroll
  for (int off = 32; off; off >>= 1) {
    ss += __shfl_down(ss, off);
    am = fmaxf(am, __shfl_down(am, off));
  }
  __shared__ float s_ss[4], s_am[4];
  if ((tid & 63) == 0) { s_ss[tid >> 6] = ss; s_am[tid >> 6] = am; }
  __syncthreads();
  ss = s_ss[0] + s_ss[1] + s_ss[2] + s_ss[3];
  am = fmaxf(fmaxf(s_am[0], s_am[1]), fmaxf(s_am[2], s_am[3]));
  float rms = rsqrtf(ss * (1.0f / D) + 1e-5f);
  float a   = fmaxf(am * rms, 1e-5f);
  float qs  = 127.0f / a;
  if (tid == 0) alpha[t] = a * (1.0f / 127.0f);
  ushort4 o;
  o.x = f2bf(fminf(fmaxf(rintf((v.x * rms) * qs), -128.0f), 127.0f));
  o.y = f2bf(fminf(fmaxf(rintf((v.y * rms) * qs), -128.0f), 127.0f));
  o.z = f2bf(fminf(fmaxf(rintf((v.z * rms) * qs), -128.0f), 127.0f));
  o.w = f2bf(fminf(fmaxf(rintf((v.w * rms) * qs), -128.0f), 127.0f));
  ((ushort4*)(xq + t * (size_t)D))[tid] = o;
}

// ---------------- rmsnorm + quant of h, in place (F=4096, bf16) ----------------
__global__ void k_actq_h(__hip_bfloat16* __restrict__ h, float* __restrict__ alpha) {
  const int F = 4096;
  size_t t = blockIdx.x;
  int tid = threadIdx.x;  // 256 threads * 16 elems
  uint4* row = (uint4*)(h + t * (size_t)F);
  uint4 u0 = row[tid], u1 = row[tid + 256];
  unsigned int uu[8] = {u0.x, u0.y, u0.z, u0.w, u1.x, u1.y, u1.z, u1.w};
  float f[16];
  #pragma unroll
  for (int i = 0; i < 8; i++) {
    f[2*i]   = bf2f(uu[i] & 0xffffu);
    f[2*i+1] = bf2f(uu[i] >> 16);
  }
  float ss = 0.0f, am = 0.0f;
  #pragma unroll
  for (int i = 0; i < 16; i++) { ss += f[i] * f[i]; am = fmaxf(am, fabsf(f[i])); }
  #pragma unroll
  for (int off = 32; off; off >>= 1) {
    ss += __shfl_down(ss, off);
    am = fmaxf(am, __shfl_down(am, off));
  }
  __shared__ float s_ss[4], s_am[4];
  if ((tid & 63) == 0) { s_ss[tid >> 6] = ss; s_am[tid >> 6] = am; }
  __syncthreads();
  ss = s_ss[0] + s_ss[1] + s_ss[2] + s_ss[3];
  am = fmaxf(fmaxf(s_am[0], s_am[1]), fmaxf(s_am[2], s_am[3]));
  float rms = rsqrtf(ss * (1.0f / F) + 1e-5f);
  float a   = fmaxf(am * rms, 1e-5f);
  float qs  = 127.0f / a;
  if (tid == 0) alpha[t] = a * (1.0f / 127.0f);
  unsigned int ou[8];
  #pragma unroll
  for (int i = 0; i < 8; i++) {
    unsigned short lo = f2bf(fminf(fmaxf(rintf((f[2*i]   * rms) * qs), -128.0f), 127.0f));
    unsigned short hi = f2bf(fminf(fmaxf(rintf((f[2*i+1] * rms) * qs), -128.0f), 127.0f));
    ou[i] = ((unsigned int)hi << 16) | (unsigned int)lo;
  }
  row[tid]       = make_uint4(ou[0], ou[1], ou[2], ou[3]);
  row[tid + 256] = make_uint4(ou[4], ou[5], ou[6], ou[7]);
}

// ======================= 256x256 8-phase MFMA GEMM =======================
// C[m,n] = sum_k A[m,k]*B[n,k]; epilogue: EPI==0: gelu(acc*alpha[m]*wdq+bias[n])->bf16
//                                         EPI==1:      acc*alpha[m]*wdq+bias[n] ->f32
// 8 waves (2M x 4N), BK=64 split into two k-halves of 32; LDS 2-buf x 2-khalf x [256][32].
// Staging: global_load_lds width16, linear LDS dest, swizzle folded into GLOBAL source;
// ds_read applies the same XOR swizzle (slot ^= (row>>1)&3) -> 2-way residual conflicts (free).
// Counted vmcnt(4) at phases 0/2 keeps 4 loads in flight; never drains in main loop.

#define GLD16(GP, LP) __builtin_amdgcn_global_load_lds( \
    (__attribute__((address_space(1))) void*)(GP), \
    (__attribute__((address_space(3))) void*)(LP), 16, 0, 0)
#define VMCNT4 asm volatile("s_waitcnt vmcnt(4)" ::: "memory")
#define VMCNT0 asm volatile("s_waitcnt vmcnt(0)" ::: "memory")
#define LGKM0  asm volatile("s_waitcnt lgkmcnt(0)" ::: "memory")

template<int EPI>
__global__ __launch_bounds__(512, 2) void k_gemm256(
    const __hip_bfloat16* __restrict__ A, const __hip_bfloat16* __restrict__ B,
    const float* __restrict__ bias, const float* __restrict__ alpha,
    const float* __restrict__ scales, int which,
    void* __restrict__ Cout, int M, int N, int K, int lgnbx)
{
  __shared__ __align__(16) __hip_bfloat16 sA[2][2][256][32];  // [buf][khalf][row][kcol]
  __shared__ __align__(16) __hip_bfloat16 sB[2][2][256][32];
  const int tid = threadIdx.x;
  const int lane = tid & 63, wid = tid >> 6;
  const int wm = wid >> 2, wn = wid & 3;            // 2 x 4 wave grid

  // XCD-aware block swizzle (gridDim.x % 8 == 0 for both shapes)
  const int nwg = gridDim.x, bid = blockIdx.x;
  const int swz = (bid & 7) * (nwg >> 3) + (bid >> 3);
  const int bx = swz & ((1 << lgnbx) - 1), by = swz >> lgnbx;
  const int m0 = by * 256, n0 = bx * 256;

  // ---- staging geometry: one GLD16 instr = 512 lanes x 16B = 128 rows x 64B ----
  const int srow  = tid >> 2;            // 0..127
  const int sslot8 = (tid & 3) * 8;      // linear LDS slot (elements)
  const int sswz8  = (((tid & 3) ^ ((srow >> 1) & 3))) * 8;  // pre-swizzled global slot
  const __hip_bfloat16* pA0 = A + (size_t)(m0 +       srow) * K + sswz8;      // khalf0 rows 0-127
  const __hip_bfloat16* pA1 = A + (size_t)(m0 + 128 + srow) * K + sswz8;      // khalf0 rows 128-255
  const __hip_bfloat16* pA2 = pA0 + 32;                                       // khalf1
  const __hip_bfloat16* pA3 = pA1 + 32;
  const __hip_bfloat16* pB0 = B + (size_t)(n0 +       srow) * K + sswz8;
  const __hip_bfloat16* pB1 = B + (size_t)(n0 + 128 + srow) * K + sswz8;
  const __hip_bfloat16* pB2 = pB0 + 32;
  const __hip_bfloat16* pB3 = pB1 + 32;

  // ---- fragment read geometry (swizzled k-slot is a per-lane constant) ----
  const int lr = lane & 15;
  const int kswz = (((lane >> 4) ^ ((lane >> 1) & 3)) << 3);   // element offset 0/8/16/24
  const int arow0 = wm * 128 + lr;
  const int brow0 = wn * 64 + lr;
  const __hip_bfloat16* sAf = &sA[0][0][0][0];
  const __hip_bfloat16* sBf = &sB[0][0][0][0];
  #define SA_(c,k,r) (sAf + (((c)*2+(k))*256 + (r))*32 + kswz)
  #define SB_(c,k,r) (sBf + (((c)*2+(k))*256 + (r))*32 + kswz)

  const int NT = K >> 6;

  // ---- prologue: stage tile 0 into buf0 (issue order = consumption order) ----
  GLD16(pA0, &sA[0][0][srow][sslot8]); GLD16(pA1, &sA[0][0][128+srow][sslot8]);
  GLD16(pB0, &sB[0][0][srow][sslot8]); GLD16(pB1, &sB[0][0][128+srow][sslot8]);
  GLD16(pA2, &sA[0][1][srow][sslot8]); GLD16(pA3, &sA[0][1][128+srow][sslot8]);
  GLD16(pB2, &sB[0][1][srow][sslot8]); GLD16(pB3, &sB[0][1][128+srow][sslot8]);
  pA0 += 64; pA1 += 64; pA2 += 64; pA3 += 64;
  pB0 += 64; pB1 += 64; pB2 += 64; pB3 += 64;

  f32x4_t acc[8][4] = {};

  for (int t = 0; t < NT; ++t) {
    const int cur = t & 1, nxt = cur ^ 1;
    const bool pf = (t + 1 < NT);
    bf16x8_t bfv[4];

    // ===== phase 0: kstep 0, m-half 0 =====  (needs Akh0(t), Bkh0(t) = oldest 4)
    VMCNT4;
    if (pf) { GLD16(pA0, &sA[nxt][0][srow][sslot8]); GLD16(pA1, &sA[nxt][0][128+srow][sslot8]); pA0 += 64; pA1 += 64; }
    __builtin_amdgcn_s_barrier();
    {
      bf16x8_t af[4];
      #pragma unroll
      for (int j = 0; j < 4; ++j) af[j] = *(const bf16x8_t*)SA_(cur, 0, arow0 + j * 16);
      #pragma unroll
      for (int n = 0; n < 4; ++n) bfv[n] = *(const bf16x8_t*)SB_(cur, 0, brow0 + n * 16);
      LGKM0; __builtin_amdgcn_sched_barrier(0);
      __builtin_amdgcn_s_setprio(1);
      #pragma unroll
      for (int j = 0; j < 4; ++j)
        #pragma unroll
        for (int n = 0; n < 4; ++n)
          acc[j][n] = __builtin_amdgcn_mfma_f32_16x16x32_bf16(af[j], bfv[n], acc[j][n], 0, 0, 0);
      __builtin_amdgcn_s_setprio(0);
    }
    __builtin_amdgcn_s_barrier();

    // ===== phase 1: kstep 0, m-half 1 =====  (reuses bfv; Akh0 already valid)
    if (pf) { GLD16(pB0, &sB[nxt][0][srow][sslot8]); GLD16(pB1, &sB[nxt][0][128+srow][sslot8]); pB0 += 64; pB1 += 64; }
    __builtin_amdgcn_s_barrier();
    {
      bf16x8_t af[4];
      #pragma unroll
      for (int j = 0; j < 4; ++j) af[j] = *(const bf16x8_t*)SA_(cur, 0, arow0 + (4 + j) * 16);
      LGKM0; __builtin_amdgcn_sched_barrier(0);
      __builtin_amdgcn_s_setprio(1);
      #pragma unroll
      for (int j = 0; j < 4; ++j)
        #pragma unroll
        for (int n = 0; n < 4; ++n)
          acc[4 + j][n] = __builtin_amdgcn_mfma_f32_16x16x32_bf16(af[j], bfv[n], acc[4 + j][n], 0, 0, 0);
      __builtin_amdgcn_s_setprio(0);
    }
    __builtin_amdgcn_s_barrier();

    // ===== phase 2: kstep 1, m-half 0 =====  (needs Akh1(t), Bkh1(t) = oldest 4)
    if (pf) { VMCNT4; GLD16(pA2, &sA[nxt][1][srow][sslot8]); GLD16(pA3, &sA[nxt][1][128+srow][sslot8]); pA2 += 64; pA3 += 64; }
    else    { VMCNT0; }
    __builtin_amdgcn_s_barrier();
    {
      bf16x8_t af[4];
      #pragma unroll
      for (int j = 0; j < 4; ++j) af[j] = *(const bf16x8_t*)SA_(cur, 1, arow0 + j * 16);
      #pragma unroll
      for (int n = 0; n < 4; ++n) bfv[n] = *(const bf16x8_t*)SB_(cur, 1, brow0 + n * 16);
      LGKM0; __builtin_amdgcn_sched_barrier(0);
      __builtin_amdgcn_s_setprio(1);
      #pragma unroll
      for (int j = 0; j < 4; ++j)
        #pragma unroll
        for (int n = 0; n < 4; ++n)
          acc[j][n] = __builtin_amdgcn_mfma_f32_16x16x32_bf16(af[j], bfv[n], acc[j][n], 0, 0, 0);
      __builtin_amdgcn_s_setprio(0);
    }
    __builtin_amdgcn_s_barrier();

    // ===== phase 3: kstep 1, m-half 1 =====
    if (pf) { GLD16(pB2, &sB[nxt][1][srow][sslot8]); GLD16(pB3, &sB[nxt][1][128+srow][sslot8]); pB2 += 64; pB3 += 64; }
    __builtin_amdgcn_s_barrier();
    {
      bf16x8_t af[4];
      #pragma unroll
      for (int j = 0; j < 4; ++j) af[j] = *(const bf16x8_t*)SA_(cur, 1, arow0 + (4 + j) * 16);
      LGKM0; __builtin_amdgcn_sched_barrier(0);
      __builtin_amdgcn_s_setprio(1);
      #pragma unroll
      for (int j = 0; j < 4; ++j)
        #pragma unroll
        for (int n = 0; n < 4; ++n)
          acc[4 + j][n] = __builtin_amdgcn_mfma_f32_16x16x32_bf16(af[j], bfv[n], acc[4 + j][n], 0, 0, 0);
      __builtin_amdgcn_s_setprio(0);
    }
    __builtin_amdgcn_s_barrier();
  }

  // ---- epilogue ----
  const float wdq = scales[which];
  const int lq4 = (lane >> 4) * 4;
  #pragma unroll
  for (int m = 0; m < 8; ++m) {
    const int rowb = m0 + wm * 128 + m * 16 + lq4;
    float al[4];
    #pragma unroll
    for (int q = 0; q < 4; ++q) al[q] = alpha[rowb + q] * wdq;
    #pragma unroll
    for (int n = 0; n < 4; ++n) {
      const int col = n0 + wn * 64 + n * 16 + lr;
      const float bb = bias[col];
      #pragma unroll
      for (int q = 0; q < 4; ++q) {
        float v = acc[m][n][q] * al[q] + bb;
        if constexpr (EPI == 0) {
          v = 0.5f * v * (1.0f + erff(v * 0.70710678118654752f));
          ((__hip_bfloat16*)Cout)[(size_t)(rowb + q) * N + col] = __float2bfloat16(v);
        } else {
          ((float*)Cout)[(size_t)(rowb + q) * N + col] = v;
        }
      }
    }
  }
  #undef SA_
  #undef SB_
}

extern "C" void kernel_launch(void* const* d_in, const int* in_sizes, int n_in,
                              void* d_out, int out_size, void* d_ws, size_t ws_size,
                              hipStream_t stream) {
  const float* x  = (const float*)d_in[0];
  const float* w1 = (const float*)d_in[1];
  const float* b1 = (const float*)d_in[2];
  const float* w2 = (const float*)d_in[3];
  const float* b2 = (const float*)d_in[4];
  const int  F = in_sizes[2];                 // 4096
  const int  D = in_sizes[4];                 // 1024
  const long T = (long)in_sizes[0] / D;       // 16384 tokens
  const long nW = (long)F * D;

  char* ws = (char*)d_ws;
  float* partials1 = (float*)ws;              // [256]
  float* partials2 = partials1 + 256;         // [256]
  float* scales    = partials2 + 256;         // [2]
  float* alpha1    = (float*)(ws + 4096);     // [T]
  float* alpha2    = alpha1 + T;              // [T]
  size_t off = 4096 + 2 * (size_t)T * sizeof(float);
  off = (off + 255) & ~(size_t)255;
  __hip_bfloat16* w1q = (__hip_bfloat16*)(ws + off); off += (size_t)nW * 2;
  __hip_bfloat16* w2q = (__hip_bfloat16*)(ws + off); off += (size_t)nW * 2;
  __hip_bfloat16* xq  = (__hip_bfloat16*)(ws + off); off += (size_t)T * D * 2;
  __hip_bfloat16* h   = (__hip_bfloat16*)(ws + off); off += (size_t)T * F * 2;
  if (ws_size < off) return;

  float invW = (float)(1.0 / (double)nW);
  k_reduce_abs<<<256, 256, 0, stream>>>(w1, nW / 4, partials1);
  k_reduce_abs<<<256, 256, 0, stream>>>(w2, nW / 4, partials2);
  k_finalize_scales<<<1, 256, 0, stream>>>(partials1, partials2, scales, invW, invW);
  k_quant_w<<<2048, 256, 0, stream>>>(w1, w1q, nW / 4, scales, 0);
  k_quant_w<<<2048, 256, 0, stream>>>(w2, w2q, nW / 4, scales, 1);
  k_actq_x<<<(unsigned)T, 256, 0, stream>>>(x, xq, alpha1);

  const int lg1 = __builtin_ctz(F / 256);     // 4
  const int lg2 = __builtin_ctz(D / 256);     // 2
  dim3 g1((unsigned)((T / 256) * (F / 256)));
  k_gemm256<0><<<g1, 512, 0, stream>>>(xq, w1q, b1, alpha1, scales, 0, h, (int)T, F, D, lg1);

  k_actq_h<<<(unsigned)T, 256, 0, stream>>>(h, alpha2);

  dim3 g2((unsigned)((T / 256) * (D / 256)));
  k_gemm256<1><<<g2, 512, 0, stream>>>(h, w2q, b2, alpha2, scales, 1, d_out, (int)T, D, F, lg2);
}

// Round 4
// 331.564 us; speedup vs baseline: 1.5410x; 1.3642x over previous
//
#include <hip/hip_runtime.h>
#include <hip/hip_bf16.h>
#include <stdint.h>

typedef int   i32x4 __attribute__((ext_vector_type(4)));
typedef float f32x4 __attribute__((ext_vector_type(4)));

__device__ __forceinline__ float blo(unsigned int u) {
  unsigned int v = u << 16; float f; __builtin_memcpy(&f, &v, 4); return f;
}
__device__ __forceinline__ float bhi(unsigned int u) {
  unsigned int v = u & 0xffff0000u; float f; __builtin_memcpy(&f, &v, 4); return f;
}
__device__ __forceinline__ unsigned short f2bf(float f) {
  __hip_bfloat16 b = __float2bfloat16(f);
  unsigned short s; __builtin_memcpy(&s, &b, 2); return s;
}
__device__ __forceinline__ int pack4q(float a, float b, float c, float d, float qm) {
  int i0 = (int)rintf(a * qm) & 255;
  int i1 = (int)rintf(b * qm) & 255;
  int i2 = (int)rintf(c * qm) & 255;
  int i3 = (int)rintf(d * qm) & 255;
  return i0 | (i1 << 8) | (i2 << 16) | (i3 << 24);
}

// ---------------- weight absmean: two-stage deterministic reduction ----------------
__global__ void k_reduce_abs(const float* __restrict__ w, long n4, float* __restrict__ partials) {
  const float4* wv = (const float4*)w;
  float s = 0.0f;
  long stride = (long)gridDim.x * blockDim.x;
  for (long i = (long)blockIdx.x * blockDim.x + threadIdx.x; i < n4; i += stride) {
    float4 v = wv[i];
    s += fabsf(v.x) + fabsf(v.y) + fabsf(v.z) + fabsf(v.w);
  }
  #pragma unroll
  for (int off = 32; off; off >>= 1) s += __shfl_down(s, off);
  __shared__ float sw[4];
  if ((threadIdx.x & 63) == 0) sw[threadIdx.x >> 6] = s;
  __syncthreads();
  if (threadIdx.x == 0) partials[blockIdx.x] = sw[0] + sw[1] + sw[2] + sw[3];
}

__global__ void k_finalize_scales(const float* __restrict__ p1, const float* __restrict__ p2,
                                  float* __restrict__ scales, float inv1, float inv2) {
  int t = threadIdx.x;
  float s1 = p1[t], s2 = p2[t];
  #pragma unroll
  for (int off = 32; off; off >>= 1) { s1 += __shfl_down(s1, off); s2 += __shfl_down(s2, off); }
  __shared__ float a1[4], a2[4];
  if ((t & 63) == 0) { a1[t >> 6] = s1; a2[t >> 6] = s2; }
  __syncthreads();
  if (t == 0) {
    scales[0] = fmaxf((a1[0]+a1[1]+a1[2]+a1[3]) * inv1, 1e-5f);
    scales[1] = fmaxf((a2[0]+a2[1]+a2[2]+a2[3]) * inv2, 1e-5f);
  }
}

// ---------------- ternary weight quant -> i8 {-1,0,1} ----------------
__global__ void k_quant_w(const float* __restrict__ w, char* __restrict__ wq,
                          long n4, const float* __restrict__ scales, int which) {
  float s = 1.0f / scales[which];
  const float4* wv = (const float4*)w;
  int* qv = (int*)wq;
  long stride = (long)gridDim.x * blockDim.x;
  for (long i = (long)blockIdx.x * blockDim.x + threadIdx.x; i < n4; i += stride) {
    float4 v = wv[i];
    int b0 = (int)fminf(fmaxf(rintf(v.x * s), -1.0f), 1.0f) & 255;
    int b1 = (int)fminf(fmaxf(rintf(v.y * s), -1.0f), 1.0f) & 255;
    int b2 = (int)fminf(fmaxf(rintf(v.z * s), -1.0f), 1.0f) & 255;
    int b3 = (int)fminf(fmaxf(rintf(v.w * s), -1.0f), 1.0f) & 255;
    qv[i] = b0 | (b1 << 8) | (b2 << 16) | (b3 << 24);
  }
}

// ---------------- rmsnorm + per-token absmax int8 quant of x -> i8 (D=1024) ----------------
__global__ void k_actq_x(const float* __restrict__ x, char* __restrict__ xq,
                         float* __restrict__ alpha) {
  const int D = 1024;
  size_t t = blockIdx.x;
  int tid = threadIdx.x;
  const float4* row = (const float4*)(x + t * (size_t)D);
  float4 v = row[tid];
  float ss = v.x*v.x + v.y*v.y + v.z*v.z + v.w*v.w;
  float am = fmaxf(fmaxf(fabsf(v.x), fabsf(v.y)), fmaxf(fabsf(v.z), fabsf(v.w)));
  #pragma unroll
  for (int off = 32; off; off >>= 1) {
    ss += __shfl_down(ss, off);
    am = fmaxf(am, __shfl_down(am, off));
  }
  __shared__ float s_ss[4], s_am[4];
  if ((tid & 63) == 0) { s_ss[tid >> 6] = ss; s_am[tid >> 6] = am; }
  __syncthreads();
  ss = s_ss[0] + s_ss[1] + s_ss[2] + s_ss[3];
  am = fmaxf(fmaxf(s_am[0], s_am[1]), fmaxf(s_am[2], s_am[3]));
  float rms = rsqrtf(ss * (1.0f / D) + 1e-5f);
  float a   = fmaxf(am * rms, 1e-5f);
  float qs  = 127.0f / a;
  if (tid == 0) alpha[t] = a * (1.0f / 127.0f);
  int b0 = (int)fminf(fmaxf(rintf((v.x * rms) * qs), -128.0f), 127.0f) & 255;
  int b1 = (int)fminf(fmaxf(rintf((v.y * rms) * qs), -128.0f), 127.0f) & 255;
  int b2 = (int)fminf(fmaxf(rintf((v.z * rms) * qs), -128.0f), 127.0f) & 255;
  int b3 = (int)fminf(fmaxf(rintf((v.w * rms) * qs), -128.0f), 127.0f) & 255;
  ((int*)xq)[t * 256 + tid] = b0 | (b1 << 8) | (b2 << 16) | (b3 << 24);
}

// ---------------- stats of h: alpha2[t] = a/127, qmul[t] = rms*127/a (F=4096) ----------------
__global__ void k_stats_h(const __hip_bfloat16* __restrict__ h,
                          float* __restrict__ alpha, float* __restrict__ qmul) {
  const int F = 4096;
  size_t t = blockIdx.x;
  int tid = threadIdx.x;  // 256 threads * 16 elems
  const uint4* row = (const uint4*)(h + t * (size_t)F);
  uint4 u0 = row[tid], u1 = row[tid + 256];
  unsigned int uu[8] = {u0.x, u0.y, u0.z, u0.w, u1.x, u1.y, u1.z, u1.w};
  float ss = 0.0f, am = 0.0f;
  #pragma unroll
  for (int i = 0; i < 8; i++) {
    float f0 = blo(uu[i]), f1 = bhi(uu[i]);
    ss += f0 * f0 + f1 * f1;
    am = fmaxf(am, fmaxf(fabsf(f0), fabsf(f1)));
  }
  #pragma unroll
  for (int off = 32; off; off >>= 1) {
    ss += __shfl_down(ss, off);
    am = fmaxf(am, __shfl_down(am, off));
  }
  __shared__ float s_ss[4], s_am[4];
  if ((tid & 63) == 0) { s_ss[tid >> 6] = ss; s_am[tid >> 6] = am; }
  __syncthreads();
  if (tid == 0) {
    ss = s_ss[0] + s_ss[1] + s_ss[2] + s_ss[3];
    am = fmaxf(fmaxf(s_am[0], s_am[1]), fmaxf(s_am[2], s_am[3]));
    float rms = rsqrtf(ss * (1.0f / F) + 1e-5f);
    float a   = fmaxf(am * rms, 1e-5f);
    alpha[t] = a * (1.0f / 127.0f);
    qmul[t]  = rms * 127.0f / a;
  }
}

// ======================= i8 MFMA GEMMs =======================
// LDS tiles: [256 rows][64 i8] per operand, 3 rotating buffers (16 KB each side/buf = 96 KB).
// XOR swizzle: 16B slot s at row r stored from global k-block (s ^ (r&3)); frag read at
// phys slot (lane>>4)^(lane&3) retrieves k-block lane>>4. Same permutation on A and B.
#define GLD16(GP, LP) __builtin_amdgcn_global_load_lds( \
    (__attribute__((address_space(1))) void*)(GP), \
    (__attribute__((address_space(3))) void*)(LP), 16, 0, 0)
#define VMCNT4 asm volatile("s_waitcnt vmcnt(4)" ::: "memory")
#define VMCNT2 asm volatile("s_waitcnt vmcnt(2)" ::: "memory")
#define VMCNT0 asm volatile("s_waitcnt vmcnt(0)" ::: "memory")
#define LGKM0  do { asm volatile("s_waitcnt lgkmcnt(0)" ::: "memory"); __builtin_amdgcn_sched_barrier(0); } while(0)

// GEMM1: H[m,n] = gelu( (sum_k xq[m,k]*w1q[n,k]) * alpha[m] * wdq + bias[n] ) -> bf16
__global__ __launch_bounds__(512, 2) void k_gemm1_i8(
    const char* __restrict__ A, const char* __restrict__ B,
    const float* __restrict__ bias, const float* __restrict__ alpha,
    const float* __restrict__ scales,
    __hip_bfloat16* __restrict__ H, int N, int K, int lgnbx)
{
  __shared__ __align__(16) char lA[3 * 16384];
  __shared__ __align__(16) char lB[3 * 16384];
  const int tid = threadIdx.x, lane = tid & 63, wid = tid >> 6;
  const int wm = wid >> 2, wn = wid & 3;
  const int nwg = gridDim.x, bid = blockIdx.x;
  const int swz = (bid & 7) * (nwg >> 3) + (bid >> 3);
  const int bx = swz & ((1 << lgnbx) - 1), by = swz >> lgnbx;
  const int m0 = by * 256, n0 = bx * 256;
  const int NT = K >> 6;

  const int srow = tid >> 2, slot = tid & 3;
  const int sswz = (slot ^ (srow & 3)) * 16;
  const char* gA0 = A + (size_t)(m0 +       srow) * K + sswz;
  const char* gA1 = A + (size_t)(m0 + 128 + srow) * K + sswz;
  const char* gB0 = B + (size_t)(n0 +       srow) * K + sswz;
  const char* gB1 = B + (size_t)(n0 + 128 + srow) * K + sswz;
  const int ldst = srow * 64 + slot * 16;

  const int lr = lane & 15;
  const int kx = ((lane >> 4) ^ (lane & 3)) * 16;
  const int aoff = (wm * 128 + lr) * 64 + kx;
  const int boff = (wn * 64  + lr) * 64 + kx;

  // prologue: stage tiles 0 and 1 (issue order per tile: A0,A1,B0,B1)
  #pragma unroll
  for (int tt = 0; tt < 2; ++tt) {
    GLD16(gA0 + 64*tt, lA + tt*16384 +        ldst);
    GLD16(gA1 + 64*tt, lA + tt*16384 + 8192 + ldst);
    GLD16(gB0 + 64*tt, lB + tt*16384 +        ldst);
    GLD16(gB1 + 64*tt, lB + tt*16384 + 8192 + ldst);
  }

  i32x4 acc[8][4] = {};
  int cur = 0, nx1 = 1, nx2 = 2;

  for (int t = 0; t < NT; ++t) {
    if (t == NT - 1) { VMCNT0; } else { VMCNT4; }   // tile t's 4 loads landed (per wave)
    __builtin_amdgcn_s_barrier();                    // -> landed for all waves
    const bool pf = (t + 2 < NT);
    if (pf) {
      GLD16(gA0 + 64*(t+2), lA + nx2*16384 +        ldst);
      GLD16(gA1 + 64*(t+2), lA + nx2*16384 + 8192 + ldst);
    }
    // phase 0: m-frags 0-3, all B
    i32x4 av[4], bv[4];
    {
      const char* pa = lA + cur*16384 + aoff;
      const char* pb = lB + cur*16384 + boff;
      #pragma unroll
      for (int j = 0; j < 4; ++j) av[j] = *(const i32x4*)(pa + j*1024);
      #pragma unroll
      for (int n = 0; n < 4; ++n) bv[n] = *(const i32x4*)(pb + n*1024);
    }
    LGKM0;
    __builtin_amdgcn_s_setprio(1);
    #pragma unroll
    for (int j = 0; j < 4; ++j)
      #pragma unroll
      for (int n = 0; n < 4; ++n)
        acc[j][n] = __builtin_amdgcn_mfma_i32_16x16x64_i8(av[j], bv[n], acc[j][n], 0, 0, 0);
    __builtin_amdgcn_s_setprio(0);
    if (pf) {
      GLD16(gB0 + 64*(t+2), lB + nx2*16384 +        ldst);
      GLD16(gB1 + 64*(t+2), lB + nx2*16384 + 8192 + ldst);
    }
    // phase 1: m-frags 4-7 (reuse bv)
    {
      const char* pa = lA + cur*16384 + aoff;
      #pragma unroll
      for (int j = 0; j < 4; ++j) av[j] = *(const i32x4*)(pa + (4+j)*1024);
    }
    LGKM0;
    __builtin_amdgcn_s_setprio(1);
    #pragma unroll
    for (int j = 0; j < 4; ++j)
      #pragma unroll
      for (int n = 0; n < 4; ++n)
        acc[4+j][n] = __builtin_amdgcn_mfma_i32_16x16x64_i8(av[j], bv[n], acc[4+j][n], 0, 0, 0);
    __builtin_amdgcn_s_setprio(0);
    int tmp = cur; cur = nx1; nx1 = nx2; nx2 = tmp;
  }

  const float wdq = scales[0];
  const int lq4 = (lane >> 4) * 4;
  #pragma unroll
  for (int m = 0; m < 8; ++m) {
    const int rowb = m0 + wm * 128 + m * 16 + lq4;
    float al[4];
    #pragma unroll
    for (int q = 0; q < 4; ++q) al[q] = alpha[rowb + q] * wdq;
    #pragma unroll
    for (int n = 0; n < 4; ++n) {
      const int col = n0 + wn * 64 + n * 16 + lr;
      const float bb = bias[col];
      #pragma unroll
      for (int q = 0; q < 4; ++q) {
        float v = (float)acc[m][n][q] * al[q] + bb;
        v = 0.5f * v * (1.0f + erff(v * 0.70710678118654752f));
        H[(size_t)(rowb + q) * N + col] = __float2bfloat16(v);
      }
    }
  }
}

// GEMM2: Out[m,n] = (sum_k q8(h[m,k])*w2q[n,k]) * alpha[m] * wdq + bias[n] -> f32
// A-operand converted bf16->i8 during reg-staging (qmul per row); B via global_load_lds.
__global__ __launch_bounds__(512, 2) void k_gemm2_i8(
    const __hip_bfloat16* __restrict__ Hs, const char* __restrict__ B,
    const float* __restrict__ bias, const float* __restrict__ alpha,
    const float* __restrict__ qmul, const float* __restrict__ scales,
    float* __restrict__ Out, int N, int K, int lgnbx)
{
  __shared__ __align__(16) char lA[3 * 16384];
  __shared__ __align__(16) char lB[3 * 16384];
  const int tid = threadIdx.x, lane = tid & 63, wid = tid >> 6;
  const int wm = wid >> 2, wn = wid & 3;
  const int nwg = gridDim.x, bid = blockIdx.x;
  const int swz = (bid & 7) * (nwg >> 3) + (bid >> 3);
  const int bx = swz & ((1 << lgnbx) - 1), by = swz >> lgnbx;
  const int m0 = by * 256, n0 = bx * 256;
  const int NT = K >> 6;

  // B staging (GLD16)
  const int srow = tid >> 2, slot = tid & 3;
  const int sswz = (slot ^ (srow & 3)) * 16;
  const char* gB0 = B + (size_t)(n0 +       srow) * K + sswz;
  const char* gB1 = B + (size_t)(n0 + 128 + srow) * K + sswz;
  const int ldst = srow * 64 + slot * 16;

  // A staging (regs + cvt): thread covers row=tid>>1, k-half (tid&1)*32 elems
  const int arow = tid >> 1, akh = (tid & 1) * 32;
  const char* gA = (const char*)(Hs + (size_t)(m0 + arow) * K + akh);  // +128B per tile
  const float qm = qmul[m0 + arow];
  const int aph0 = (((akh >> 4)    ) ^ (arow & 3)) * 16;
  const int aph1 = (((akh >> 4) + 1) ^ (arow & 3)) * 16;
  const int awb = arow * 64;

  const int lr = lane & 15;
  const int kx = ((lane >> 4) ^ (lane & 3)) * 16;
  const int aoff = (wm * 128 + lr) * 64 + kx;
  const int boff = (wn * 64  + lr) * 64 + kx;

  uint4 a0, a1, a2, a3;
  // prologue: A(0) regs; B(0); B(1)
  { const uint4* ga = (const uint4*)gA; a0 = ga[0]; a1 = ga[1]; a2 = ga[2]; a3 = ga[3]; }
  GLD16(gB0,      lB +            ldst);
  GLD16(gB1,      lB +     8192 + ldst);
  GLD16(gB0 + 64, lB + 16384 +        ldst);
  GLD16(gB1 + 64, lB + 16384 + 8192 + ldst);
  VMCNT4;  // A(0) regs landed
  {
    i32x4 w0, w1;
    w0[0] = pack4q(blo(a0.x), bhi(a0.x), blo(a0.y), bhi(a0.y), qm);
    w0[1] = pack4q(blo(a0.z), bhi(a0.z), blo(a0.w), bhi(a0.w), qm);
    w0[2] = pack4q(blo(a1.x), bhi(a1.x), blo(a1.y), bhi(a1.y), qm);
    w0[3] = pack4q(blo(a1.z), bhi(a1.z), blo(a1.w), bhi(a1.w), qm);
    w1[0] = pack4q(blo(a2.x), bhi(a2.x), blo(a2.y), bhi(a2.y), qm);
    w1[1] = pack4q(blo(a2.z), bhi(a2.z), blo(a2.w), bhi(a2.w), qm);
    w1[2] = pack4q(blo(a3.x), bhi(a3.x), blo(a3.y), bhi(a3.y), qm);
    w1[3] = pack4q(blo(a3.z), bhi(a3.z), blo(a3.w), bhi(a3.w), qm);
    *(i32x4*)(lA + awb + aph0) = w0;
    *(i32x4*)(lA + awb + aph1) = w1;
  }
  VMCNT2;  // B(0) landed
  LGKM0;   // A(0) ds_writes done
  __builtin_amdgcn_s_barrier();

  i32x4 acc[8][4] = {};
  int cur = 0, nx1 = 1, nx2 = 2;

  for (int t = 0; t < NT; ++t) {
    if (t + 1 < NT) {  // issue A(t+1) regs
      const uint4* ga = (const uint4*)(gA + (size_t)128 * (t + 1));
      a0 = ga[0]; a1 = ga[1]; a2 = ga[2]; a3 = ga[3];
    }
    // phase 0
    i32x4 av[4], bv[4];
    {
      const char* pa = lA + cur*16384 + aoff;
      const char* pb = lB + cur*16384 + boff;
      #pragma unroll
      for (int j = 0; j < 4; ++j) av[j] = *(const i32x4*)(pa + j*1024);
      #pragma unroll
      for (int n = 0; n < 4; ++n) bv[n] = *(const i32x4*)(pb + n*1024);
    }
    LGKM0;
    __builtin_amdgcn_s_setprio(1);
    #pragma unroll
    for (int j = 0; j < 4; ++j)
      #pragma unroll
      for (int n = 0; n < 4; ++n)
        acc[j][n] = __builtin_amdgcn_mfma_i32_16x16x64_i8(av[j], bv[n], acc[j][n], 0, 0, 0);
    __builtin_amdgcn_s_setprio(0);
    VMCNT0;  // A(t+1) regs + B(t+1) staged
    if (t + 1 < NT) {
      i32x4 w0, w1;
      w0[0] = pack4q(blo(a0.x), bhi(a0.x), blo(a0.y), bhi(a0.y), qm);
      w0[1] = pack4q(blo(a0.z), bhi(a0.z), blo(a0.w), bhi(a0.w), qm);
      w0[2] = pack4q(blo(a1.x), bhi(a1.x), blo(a1.y), bhi(a1.y), qm);
      w0[3] = pack4q(blo(a1.z), bhi(a1.z), blo(a1.w), bhi(a1.w), qm);
      w1[0] = pack4q(blo(a2.x), bhi(a2.x), blo(a2.y), bhi(a2.y), qm);
      w1[1] = pack4q(blo(a2.z), bhi(a2.z), blo(a2.w), bhi(a2.w), qm);
      w1[2] = pack4q(blo(a3.x), bhi(a3.x), blo(a3.y), bhi(a3.y), qm);
      w1[3] = pack4q(blo(a3.z), bhi(a3.z), blo(a3.w), bhi(a3.w), qm);
      char* dst = lA + nx1*16384 + awb;
      *(i32x4*)(dst + aph0) = w0;
      *(i32x4*)(dst + aph1) = w1;
    }
    if (t + 2 < NT) {
      GLD16(gB0 + 64*(t+2), lB + nx2*16384 +        ldst);
      GLD16(gB1 + 64*(t+2), lB + nx2*16384 + 8192 + ldst);
    }
    // phase 1 (reuse bv)
    {
      const char* pa = lA + cur*16384 + aoff;
      #pragma unroll
      for (int j = 0; j < 4; ++j) av[j] = *(const i32x4*)(pa + (4+j)*1024);
    }
    LGKM0;   // also covers my A(t+1) ds_writes before end barrier
    __builtin_amdgcn_s_setprio(1);
    #pragma unroll
    for (int j = 0; j < 4; ++j)
      #pragma unroll
      for (int n = 0; n < 4; ++n)
        acc[4+j][n] = __builtin_amdgcn_mfma_i32_16x16x64_i8(av[j], bv[n], acc[4+j][n], 0, 0, 0);
    __builtin_amdgcn_s_setprio(0);
    __builtin_amdgcn_s_barrier();
    int tmp = cur; cur = nx1; nx1 = nx2; nx2 = tmp;
  }

  const float wdq = scales[1];
  const int lq4 = (lane >> 4) * 4;
  #pragma unroll
  for (int m = 0; m < 8; ++m) {
    const int rowb = m0 + wm * 128 + m * 16 + lq4;
    float al[4];
    #pragma unroll
    for (int q = 0; q < 4; ++q) al[q] = alpha[rowb + q] * wdq;
    #pragma unroll
    for (int n = 0; n < 4; ++n) {
      const int col = n0 + wn * 64 + n * 16 + lr;
      const float bb = bias[col];
      #pragma unroll
      for (int q = 0; q < 4; ++q)
        Out[(size_t)(rowb + q) * N + col] = (float)acc[m][n][q] * al[q] + bb;
    }
  }
}

extern "C" void kernel_launch(void* const* d_in, const int* in_sizes, int n_in,
                              void* d_out, int out_size, void* d_ws, size_t ws_size,
                              hipStream_t stream) {
  const float* x  = (const float*)d_in[0];
  const float* w1 = (const float*)d_in[1];
  const float* b1 = (const float*)d_in[2];
  const float* w2 = (const float*)d_in[3];
  const float* b2 = (const float*)d_in[4];
  const int  F = in_sizes[2];                 // 4096
  const int  D = in_sizes[4];                 // 1024
  const long T = (long)in_sizes[0] / D;       // 16384 tokens
  const long nW = (long)F * D;

  char* ws = (char*)d_ws;
  float* partials1 = (float*)ws;
  float* partials2 = partials1 + 256;
  float* scales    = partials2 + 256;
  float* alpha1 = (float*)(ws + 4096);        // [T]
  float* alpha2 = alpha1 + T;                 // [T]
  float* qmul   = alpha2 + T;                 // [T]
  size_t off = 4096 + 3 * (size_t)T * sizeof(float);
  off = (off + 255) & ~(size_t)255;
  char* w1q = ws + off; off += (size_t)nW;
  char* w2q = ws + off; off += (size_t)nW;
  char* xq  = ws + off; off += (size_t)T * D;
  off = (off + 255) & ~(size_t)255;
  __hip_bfloat16* h = (__hip_bfloat16*)(ws + off); off += (size_t)T * F * 2;
  if (ws_size < off) return;

  float invW = (float)(1.0 / (double)nW);
  k_reduce_abs<<<256, 256, 0, stream>>>(w1, nW / 4, partials1);
  k_reduce_abs<<<256, 256, 0, stream>>>(w2, nW / 4, partials2);
  k_finalize_scales<<<1, 256, 0, stream>>>(partials1, partials2, scales, invW, invW);
  k_quant_w<<<2048, 256, 0, stream>>>(w1, w1q, nW / 4, scales, 0);
  k_quant_w<<<2048, 256, 0, stream>>>(w2, w2q, nW / 4, scales, 1);
  k_actq_x<<<(unsigned)T, 256, 0, stream>>>(x, xq, alpha1);

  dim3 g1((unsigned)((T / 256) * (F / 256)));  // 1024 blocks
  k_gemm1_i8<<<g1, 512, 0, stream>>>(xq, w1q, b1, alpha1, scales, h, F, D,
                                     __builtin_ctz(F / 256));

  k_stats_h<<<(unsigned)T, 256, 0, stream>>>(h, alpha2, qmul);

  dim3 g2((unsigned)((T / 256) * (D / 256)));  // 256 blocks
  k_gemm2_i8<<<g2, 512, 0, stream>>>(h, w2q, b2, alpha2, qmul, scales, (float*)d_out, D, F,
                                     __builtin_ctz(D / 256));
}

// Round 5
// 257.908 us; speedup vs baseline: 1.9811x; 1.2856x over previous
//
#include <hip/hip_runtime.h>
#include <hip/hip_bf16.h>
#include <stdint.h>

typedef int i32x4 __attribute__((ext_vector_type(4)));

__device__ __forceinline__ float blo(unsigned int u) {
  unsigned int v = u << 16; float f; __builtin_memcpy(&f, &v, 4); return f;
}
__device__ __forceinline__ float bhi(unsigned int u) {
  unsigned int v = u & 0xffff0000u; float f; __builtin_memcpy(&f, &v, 4); return f;
}
__device__ __forceinline__ int pack4q(float a, float b, float c, float d, float qm) {
  int i0 = (int)rintf(a * qm) & 255;
  int i1 = (int)rintf(b * qm) & 255;
  int i2 = (int)rintf(c * qm) & 255;
  int i3 = (int)rintf(d * qm) & 255;
  return i0 | (i1 << 8) | (i2 << 16) | (i3 << 24);
}

__device__ __forceinline__ float fast_gelu(float v) {
  // exact-erf GELU via Abramowitz-Stegun 7.1.26 (|erf err| <= 1.5e-7)
  float u = v * 0.70710678118654752f;
  float s = fabsf(u);
  float den = fmaf(0.3275911f, s, 1.0f);
  float t;
  asm("v_rcp_f32 %0, %1" : "=v"(t) : "v"(den));
  float p = t * fmaf(t, fmaf(t, fmaf(t, fmaf(t, 1.061405429f, -1.453152027f),
                                     1.421413741f), -0.284496736f), 0.254829592f);
  float e = fmaf(-p, __expf(-u * u), 1.0f);
  float er = copysignf(e, u);
  return 0.5f * v * (1.0f + er);
}

// ---------------- weight absmean: two-stage deterministic reduction ----------------
__global__ void k_reduce_abs(const float* __restrict__ w, long n4, float* __restrict__ partials) {
  const float4* wv = (const float4*)w;
  float s = 0.0f;
  long stride = (long)gridDim.x * blockDim.x;
  for (long i = (long)blockIdx.x * blockDim.x + threadIdx.x; i < n4; i += stride) {
    float4 v = wv[i];
    s += fabsf(v.x) + fabsf(v.y) + fabsf(v.z) + fabsf(v.w);
  }
  #pragma unroll
  for (int off = 32; off; off >>= 1) s += __shfl_down(s, off);
  __shared__ float sw[4];
  if ((threadIdx.x & 63) == 0) sw[threadIdx.x >> 6] = s;
  __syncthreads();
  if (threadIdx.x == 0) partials[blockIdx.x] = sw[0] + sw[1] + sw[2] + sw[3];
}

__global__ void k_finalize_scales(const float* __restrict__ p1, const float* __restrict__ p2,
                                  float* __restrict__ scales, float inv1, float inv2) {
  int t = threadIdx.x;
  float s1 = p1[t], s2 = p2[t];
  #pragma unroll
  for (int off = 32; off; off >>= 1) { s1 += __shfl_down(s1, off); s2 += __shfl_down(s2, off); }
  __shared__ float a1[4], a2[4];
  if ((t & 63) == 0) { a1[t >> 6] = s1; a2[t >> 6] = s2; }
  __syncthreads();
  if (t == 0) {
    scales[0] = fmaxf((a1[0]+a1[1]+a1[2]+a1[3]) * inv1, 1e-5f);
    scales[1] = fmaxf((a2[0]+a2[1]+a2[2]+a2[3]) * inv2, 1e-5f);
  }
}

// ---------------- ternary weight quant -> i8 {-1,0,1} ----------------
__global__ void k_quant_w(const float* __restrict__ w, char* __restrict__ wq,
                          long n4, const float* __restrict__ scales, int which) {
  float s = 1.0f / scales[which];
  const float4* wv = (const float4*)w;
  int* qv = (int*)wq;
  long stride = (long)gridDim.x * blockDim.x;
  for (long i = (long)blockIdx.x * blockDim.x + threadIdx.x; i < n4; i += stride) {
    float4 v = wv[i];
    int b0 = (int)fminf(fmaxf(rintf(v.x * s), -1.0f), 1.0f) & 255;
    int b1 = (int)fminf(fmaxf(rintf(v.y * s), -1.0f), 1.0f) & 255;
    int b2 = (int)fminf(fmaxf(rintf(v.z * s), -1.0f), 1.0f) & 255;
    int b3 = (int)fminf(fmaxf(rintf(v.w * s), -1.0f), 1.0f) & 255;
    qv[i] = b0 | (b1 << 8) | (b2 << 16) | (b3 << 24);
  }
}

// ---------------- rmsnorm + per-token absmax int8 quant of x -> i8 (D=1024) ----------------
__global__ void k_actq_x(const float* __restrict__ x, char* __restrict__ xq,
                         float* __restrict__ alpha) {
  const int D = 1024;
  size_t t = blockIdx.x;
  int tid = threadIdx.x;
  const float4* row = (const float4*)(x + t * (size_t)D);
  float4 v = row[tid];
  float ss = v.x*v.x + v.y*v.y + v.z*v.z + v.w*v.w;
  float am = fmaxf(fmaxf(fabsf(v.x), fabsf(v.y)), fmaxf(fabsf(v.z), fabsf(v.w)));
  #pragma unroll
  for (int off = 32; off; off >>= 1) {
    ss += __shfl_down(ss, off);
    am = fmaxf(am, __shfl_down(am, off));
  }
  __shared__ float s_ss[4], s_am[4];
  if ((tid & 63) == 0) { s_ss[tid >> 6] = ss; s_am[tid >> 6] = am; }
  __syncthreads();
  ss = s_ss[0] + s_ss[1] + s_ss[2] + s_ss[3];
  am = fmaxf(fmaxf(s_am[0], s_am[1]), fmaxf(s_am[2], s_am[3]));
  float rms = rsqrtf(ss * (1.0f / D) + 1e-5f);
  float a   = fmaxf(am * rms, 1e-5f);
  float qs  = 127.0f / a;
  if (tid == 0) alpha[t] = a * (1.0f / 127.0f);
  int b0 = (int)fminf(fmaxf(rintf((v.x * rms) * qs), -128.0f), 127.0f) & 255;
  int b1 = (int)fminf(fmaxf(rintf((v.y * rms) * qs), -128.0f), 127.0f) & 255;
  int b2 = (int)fminf(fmaxf(rintf((v.z * rms) * qs), -128.0f), 127.0f) & 255;
  int b3 = (int)fminf(fmaxf(rintf((v.w * rms) * qs), -128.0f), 127.0f) & 255;
  ((int*)xq)[t * 256 + tid] = b0 | (b1 << 8) | (b2 << 16) | (b3 << 24);
}

// ------- rmsnorm + absmax quant of h, IN PLACE: first F bytes of each bf16 row become i8 -------
__global__ void k_actq_h(__hip_bfloat16* __restrict__ h, float* __restrict__ alpha) {
  const int F = 4096;
  size_t t = blockIdx.x;
  int tid = threadIdx.x;  // 256 threads * 16 elems
  char* rb = (char*)(h + t * (size_t)F);
  const uint4* row = (const uint4*)rb;
  uint4 u0 = row[tid], u1 = row[tid + 256];
  unsigned int uu[8] = {u0.x, u0.y, u0.z, u0.w, u1.x, u1.y, u1.z, u1.w};
  float ss = 0.0f, am = 0.0f;
  #pragma unroll
  for (int i = 0; i < 8; i++) {
    float f0 = blo(uu[i]), f1 = bhi(uu[i]);
    ss += f0 * f0 + f1 * f1;
    am = fmaxf(am, fmaxf(fabsf(f0), fabsf(f1)));
  }
  #pragma unroll
  for (int off = 32; off; off >>= 1) {
    ss += __shfl_down(ss, off);
    am = fmaxf(am, __shfl_down(am, off));
  }
  __shared__ float s_ss[4], s_am[4];
  if ((tid & 63) == 0) { s_ss[tid >> 6] = ss; s_am[tid >> 6] = am; }
  __syncthreads();   // also orders: all row reads complete before in-place writes
  ss = s_ss[0] + s_ss[1] + s_ss[2] + s_ss[3];
  am = fmaxf(fmaxf(s_am[0], s_am[1]), fmaxf(s_am[2], s_am[3]));
  float rms = rsqrtf(ss * (1.0f / F) + 1e-5f);
  float a   = fmaxf(am * rms, 1e-5f);
  float qm  = rms * (127.0f / a);
  if (tid == 0) alpha[t] = a * (1.0f / 127.0f);
  uint2 w0, w1;
  w0.x = (unsigned)pack4q(blo(uu[0]), bhi(uu[0]), blo(uu[1]), bhi(uu[1]), qm);
  w0.y = (unsigned)pack4q(blo(uu[2]), bhi(uu[2]), blo(uu[3]), bhi(uu[3]), qm);
  w1.x = (unsigned)pack4q(blo(uu[4]), bhi(uu[4]), blo(uu[5]), bhi(uu[5]), qm);
  w1.y = (unsigned)pack4q(blo(uu[6]), bhi(uu[6]), blo(uu[7]), bhi(uu[7]), qm);
  *(uint2*)(rb + 8 * tid) = w0;          // i8 elems [8tid..8tid+7]
  *(uint2*)(rb + 2048 + 8 * tid) = w1;   // i8 elems [2048+8tid..]
}

// ======================= i8 MFMA GEMM, 128x256 tile, 2-buffer =======================
// C[m,n] = sum_k A[m,k]*B[n,k].  8 waves (2m x 4n), wave tile 64x64, BK=64.
// LDS 48 KB -> 2-3 blocks/CU.  One barrier + one vmcnt(0) per K-tile; prefetch
// of tile t+1 issued right after the barrier (1 tile of compute covers latency,
// plus co-resident blocks).  Swizzle (both sides): 16B chunk c of row r stored
// at slot c^((r>>1)&3) -> each 16-lane group spreads over all 8 bank-quads (2/quad = free).
#define GLD16(GP, LP) __builtin_amdgcn_global_load_lds( \
    (__attribute__((address_space(1))) void*)(GP), \
    (__attribute__((address_space(3))) void*)(LP), 16, 0, 0)
#define VMCNT0 asm volatile("s_waitcnt vmcnt(0)" ::: "memory")
#define LGKM0  do { asm volatile("s_waitcnt lgkmcnt(0)" ::: "memory"); __builtin_amdgcn_sched_barrier(0); } while(0)

template<int EPI>   // 0: gelu -> bf16 H    1: -> f32 Out
__global__ __launch_bounds__(512, 4) void k_gemm_i8(
    const char* __restrict__ A, int lda,          // A row stride in BYTES
    const char* __restrict__ B,                   // B packed, row stride = K bytes
    const float* __restrict__ bias, const float* __restrict__ alpha,
    const float* __restrict__ scales, int which,
    void* __restrict__ Cout, int N, int K, int lgnbx)
{
  __shared__ __align__(16) char lA[2 * 8192];    // [buf][128 rows][64 B]
  __shared__ __align__(16) char lB[2 * 16384];   // [buf][256 rows][64 B]
  const int tid = threadIdx.x, lane = tid & 63, wid = tid >> 6;
  const int wm = wid >> 2, wn = wid & 3;
  const int nwg = gridDim.x, bid = blockIdx.x;
  const int swz = (bid & 7) * (nwg >> 3) + (bid >> 3);
  const int bx = swz & ((1 << lgnbx) - 1), by = swz >> lgnbx;
  const int m0 = by * 128, n0 = bx * 256;
  const int NT = K >> 6;

  // staging: thread covers (srow, 16B slot); pre-swizzled global chunk
  const int srow = tid >> 2, slot = tid & 3;
  const int sswz = (slot ^ ((srow >> 1) & 3)) * 16;
  const char* gA0 = A + (size_t)(m0 +       srow) * lda + sswz;
  const char* gB0 = B + (size_t)(n0 +       srow) * K   + sswz;
  const char* gB1 = B + (size_t)(n0 + 128 + srow) * K   + sswz;
  const int ldst = srow * 64 + slot * 16;

  // fragment reads: lane reads k-chunk lane>>4 of row (.. + lr); phys slot applies same XOR
  const int lr = lane & 15;
  const int kx = ((lane >> 4) ^ ((lane >> 1) & 3)) * 16;
  const int aoff = (wm * 64 + lr) * 64 + kx;
  const int boff = (wn * 64 + lr) * 64 + kx;

  // prologue: tile 0 -> buf 0
  GLD16(gA0, lA + ldst);
  GLD16(gB0, lB + ldst);
  GLD16(gB1, lB + 8192 + ldst);

  i32x4 acc[4][4] = {};
  for (int t = 0; t < NT; ++t) {
    const int cur = t & 1, nxt = cur ^ 1;
    VMCNT0;                              // tile t's 3 loads landed (this wave's slice)
    __builtin_amdgcn_s_barrier();        // all slices landed; all waves done with buf[nxt]
    if (t + 1 < NT) {
      GLD16(gA0 + 64 * (t + 1), lA + nxt * 8192 + ldst);
      GLD16(gB0 + 64 * (t + 1), lB + nxt * 16384 + ldst);
      GLD16(gB1 + 64 * (t + 1), lB + nxt * 16384 + 8192 + ldst);
    }
    i32x4 av[4], bv[4];
    {
      const char* pa = lA + cur * 8192 + aoff;
      const char* pb = lB + cur * 16384 + boff;
      #pragma unroll
      for (int j = 0; j < 4; ++j) av[j] = *(const i32x4*)(pa + j * 1024);
      #pragma unroll
      for (int n = 0; n < 4; ++n) bv[n] = *(const i32x4*)(pb + n * 1024);
    }
    LGKM0;
    __builtin_amdgcn_s_setprio(1);
    #pragma unroll
    for (int j = 0; j < 4; ++j)
      #pragma unroll
      for (int n = 0; n < 4; ++n)
        acc[j][n] = __builtin_amdgcn_mfma_i32_16x16x64_i8(av[j], bv[n], acc[j][n], 0, 0, 0);
    __builtin_amdgcn_s_setprio(0);
  }

  const float wdq = scales[which];
  const int lq4 = (lane >> 4) * 4;
  #pragma unroll
  for (int m = 0; m < 4; ++m) {
    const int rowb = m0 + wm * 64 + m * 16 + lq4;
    float al[4];
    #pragma unroll
    for (int q = 0; q < 4; ++q) al[q] = alpha[rowb + q] * wdq;
    #pragma unroll
    for (int n = 0; n < 4; ++n) {
      const int col = n0 + wn * 64 + n * 16 + lr;
      const float bb = bias[col];
      #pragma unroll
      for (int q = 0; q < 4; ++q) {
        float v = (float)acc[m][n][q] * al[q] + bb;
        if constexpr (EPI == 0) {
          ((__hip_bfloat16*)Cout)[(size_t)(rowb + q) * N + col] = __float2bfloat16(fast_gelu(v));
        } else {
          ((float*)Cout)[(size_t)(rowb + q) * N + col] = v;
        }
      }
    }
  }
}

extern "C" void kernel_launch(void* const* d_in, const int* in_sizes, int n_in,
                              void* d_out, int out_size, void* d_ws, size_t ws_size,
                              hipStream_t stream) {
  const float* x  = (const float*)d_in[0];
  const float* w1 = (const float*)d_in[1];
  const float* b1 = (const float*)d_in[2];
  const float* w2 = (const float*)d_in[3];
  const float* b2 = (const float*)d_in[4];
  const int  F = in_sizes[2];                 // 4096
  const int  D = in_sizes[4];                 // 1024
  const long T = (long)in_sizes[0] / D;       // 16384 tokens
  const long nW = (long)F * D;

  char* ws = (char*)d_ws;
  float* partials1 = (float*)ws;
  float* partials2 = partials1 + 256;
  float* scales    = partials2 + 256;
  float* alpha1 = (float*)(ws + 4096);        // [T]
  float* alpha2 = alpha1 + T;                 // [T]
  size_t off = 4096 + 2 * (size_t)T * sizeof(float);
  off = (off + 255) & ~(size_t)255;
  char* w1q = ws + off; off += (size_t)nW;
  char* w2q = ws + off; off += (size_t)nW;
  char* xq  = ws + off; off += (size_t)T * D;
  off = (off + 255) & ~(size_t)255;
  __hip_bfloat16* h = (__hip_bfloat16*)(ws + off); off += (size_t)T * F * 2;
  if (ws_size < off) return;

  float invW = (float)(1.0 / (double)nW);
  k_reduce_abs<<<256, 256, 0, stream>>>(w1, nW / 4, partials1);
  k_reduce_abs<<<256, 256, 0, stream>>>(w2, nW / 4, partials2);
  k_finalize_scales<<<1, 256, 0, stream>>>(partials1, partials2, scales, invW, invW);
  k_quant_w<<<2048, 256, 0, stream>>>(w1, w1q, nW / 4, scales, 0);
  k_quant_w<<<2048, 256, 0, stream>>>(w2, w2q, nW / 4, scales, 1);
  k_actq_x<<<(unsigned)T, 256, 0, stream>>>(x, xq, alpha1);

  // GEMM1: [T x D] i8 @ [F x D]^T i8 -> gelu -> bf16 h
  dim3 g1((unsigned)((T / 128) * (F / 256)));  // 2048 blocks
  k_gemm_i8<0><<<g1, 512, 0, stream>>>(xq, D, w1q, b1, alpha1, scales, 0,
                                       h, F, D, __builtin_ctz(F / 256));

  // rmsnorm+quant h in place (bf16 row -> leading i8 row, stride stays F*2 bytes)
  k_actq_h<<<(unsigned)T, 256, 0, stream>>>(h, alpha2);

  // GEMM2: [T x F] i8 (stride 2F) @ [D x F]^T i8 -> f32 out
  dim3 g2((unsigned)((T / 128) * (D / 256)));  // 512 blocks
  k_gemm_i8<1><<<g2, 512, 0, stream>>>((const char*)h, F * 2, w2q, b2, alpha2, scales, 1,
                                       (float*)d_out, D, F, __builtin_ctz(D / 256));
}

// Round 6
// 244.387 us; speedup vs baseline: 2.0907x; 1.0553x over previous
//
#include <hip/hip_runtime.h>
#include <hip/hip_bf16.h>
#include <stdint.h>

typedef int i32x4 __attribute__((ext_vector_type(4)));

__device__ __forceinline__ float blo(unsigned int u) {
  unsigned int v = u << 16; float f; __builtin_memcpy(&f, &v, 4); return f;
}
__device__ __forceinline__ float bhi(unsigned int u) {
  unsigned int v = u & 0xffff0000u; float f; __builtin_memcpy(&f, &v, 4); return f;
}
__device__ __forceinline__ int pack4q(float a, float b, float c, float d, float qm) {
  int i0 = (int)rintf(a * qm) & 255;
  int i1 = (int)rintf(b * qm) & 255;
  int i2 = (int)rintf(c * qm) & 255;
  int i3 = (int)rintf(d * qm) & 255;
  return i0 | (i1 << 8) | (i2 << 16) | (i3 << 24);
}

__device__ __forceinline__ float fast_gelu(float v) {
  // exact-erf GELU via Abramowitz-Stegun 7.1.26 (|erf err| <= 1.5e-7)
  float u = v * 0.70710678118654752f;
  float s = fabsf(u);
  float den = fmaf(0.3275911f, s, 1.0f);
  float t;
  asm("v_rcp_f32 %0, %1" : "=v"(t) : "v"(den));
  float p = t * fmaf(t, fmaf(t, fmaf(t, fmaf(t, 1.061405429f, -1.453152027f),
                                     1.421413741f), -0.284496736f), 0.254829592f);
  float e = fmaf(-p, __expf(-u * u), 1.0f);
  float er = copysignf(e, u);
  return 0.5f * v * (1.0f + er);
}

// ------------- weight absmean: both matrices in one dispatch (256 blocks each) -------------
__global__ void k_reduce_abs2(const float* __restrict__ w1, const float* __restrict__ w2,
                              long n4, float* __restrict__ partials) {
  const int half = gridDim.x >> 1;
  const float* w = (blockIdx.x < half) ? w1 : w2;
  int b = (blockIdx.x < half) ? blockIdx.x : blockIdx.x - half;
  const float4* wv = (const float4*)w;
  float s = 0.0f;
  long stride = (long)half * blockDim.x;
  for (long i = (long)b * blockDim.x + threadIdx.x; i < n4; i += stride) {
    float4 v = wv[i];
    s += fabsf(v.x) + fabsf(v.y) + fabsf(v.z) + fabsf(v.w);
  }
  #pragma unroll
  for (int off = 32; off; off >>= 1) s += __shfl_down(s, off);
  __shared__ float sw[4];
  if ((threadIdx.x & 63) == 0) sw[threadIdx.x >> 6] = s;
  __syncthreads();
  if (threadIdx.x == 0) partials[blockIdx.x] = sw[0] + sw[1] + sw[2] + sw[3];
}

__global__ void k_finalize_scales(const float* __restrict__ p1, const float* __restrict__ p2,
                                  float* __restrict__ scales, float inv1, float inv2) {
  int t = threadIdx.x;
  float s1 = p1[t], s2 = p2[t];
  #pragma unroll
  for (int off = 32; off; off >>= 1) { s1 += __shfl_down(s1, off); s2 += __shfl_down(s2, off); }
  __shared__ float a1[4], a2[4];
  if ((t & 63) == 0) { a1[t >> 6] = s1; a2[t >> 6] = s2; }
  __syncthreads();
  if (t == 0) {
    scales[0] = fmaxf((a1[0]+a1[1]+a1[2]+a1[3]) * inv1, 1e-5f);
    scales[1] = fmaxf((a2[0]+a2[1]+a2[2]+a2[3]) * inv2, 1e-5f);
  }
}

// ------------- ternary weight quant -> i8 {-1,0,1}, both matrices in one dispatch -------------
__global__ void k_quant_w2(const float* __restrict__ w1, char* __restrict__ wq1,
                           const float* __restrict__ w2, char* __restrict__ wq2,
                           long n4, const float* __restrict__ scales) {
  const int half = gridDim.x >> 1;
  const bool first = blockIdx.x < half;
  const float* w = first ? w1 : w2;
  char* wq = first ? wq1 : wq2;
  int b = first ? blockIdx.x : blockIdx.x - half;
  float s = 1.0f / scales[first ? 0 : 1];
  const float4* wv = (const float4*)w;
  int* qv = (int*)wq;
  long stride = (long)half * blockDim.x;
  for (long i = (long)b * blockDim.x + threadIdx.x; i < n4; i += stride) {
    float4 v = wv[i];
    int b0 = (int)fminf(fmaxf(rintf(v.x * s), -1.0f), 1.0f) & 255;
    int b1 = (int)fminf(fmaxf(rintf(v.y * s), -1.0f), 1.0f) & 255;
    int b2 = (int)fminf(fmaxf(rintf(v.z * s), -1.0f), 1.0f) & 255;
    int b3 = (int)fminf(fmaxf(rintf(v.w * s), -1.0f), 1.0f) & 255;
    qv[i] = b0 | (b1 << 8) | (b2 << 16) | (b3 << 24);
  }
}

// ---------------- rmsnorm + per-token absmax int8 quant of x -> i8 (D=1024) ----------------
__global__ void k_actq_x(const float* __restrict__ x, char* __restrict__ xq,
                         float* __restrict__ alpha) {
  const int D = 1024;
  size_t t = blockIdx.x;
  int tid = threadIdx.x;
  const float4* row = (const float4*)(x + t * (size_t)D);
  float4 v = row[tid];
  float ss = v.x*v.x + v.y*v.y + v.z*v.z + v.w*v.w;
  float am = fmaxf(fmaxf(fabsf(v.x), fabsf(v.y)), fmaxf(fabsf(v.z), fabsf(v.w)));
  #pragma unroll
  for (int off = 32; off; off >>= 1) {
    ss += __shfl_down(ss, off);
    am = fmaxf(am, __shfl_down(am, off));
  }
  __shared__ float s_ss[4], s_am[4];
  if ((tid & 63) == 0) { s_ss[tid >> 6] = ss; s_am[tid >> 6] = am; }
  __syncthreads();
  ss = s_ss[0] + s_ss[1] + s_ss[2] + s_ss[3];
  am = fmaxf(fmaxf(s_am[0], s_am[1]), fmaxf(s_am[2], s_am[3]));
  float rms = rsqrtf(ss * (1.0f / D) + 1e-5f);
  float a   = fmaxf(am * rms, 1e-5f);
  float qs  = 127.0f / a;
  if (tid == 0) alpha[t] = a * (1.0f / 127.0f);
  int b0 = (int)fminf(fmaxf(rintf((v.x * rms) * qs), -128.0f), 127.0f) & 255;
  int b1 = (int)fminf(fmaxf(rintf((v.y * rms) * qs), -128.0f), 127.0f) & 255;
  int b2 = (int)fminf(fmaxf(rintf((v.z * rms) * qs), -128.0f), 127.0f) & 255;
  int b3 = (int)fminf(fmaxf(rintf((v.w * rms) * qs), -128.0f), 127.0f) & 255;
  ((int*)xq)[t * 256 + tid] = b0 | (b1 << 8) | (b2 << 16) | (b3 << 24);
}

// ------- rmsnorm + absmax quant of h, IN PLACE: first F bytes of each bf16 row become i8 -------
__global__ void k_actq_h(__hip_bfloat16* __restrict__ h, float* __restrict__ alpha) {
  const int F = 4096;
  size_t t = blockIdx.x;
  int tid = threadIdx.x;  // 256 threads * 16 elems
  char* rb = (char*)(h + t * (size_t)F);
  const uint4* row = (const uint4*)rb;
  uint4 u0 = row[tid], u1 = row[tid + 256];
  unsigned int uu[8] = {u0.x, u0.y, u0.z, u0.w, u1.x, u1.y, u1.z, u1.w};
  float ss = 0.0f, am = 0.0f;
  #pragma unroll
  for (int i = 0; i < 8; i++) {
    float f0 = blo(uu[i]), f1 = bhi(uu[i]);
    ss += f0 * f0 + f1 * f1;
    am = fmaxf(am, fmaxf(fabsf(f0), fabsf(f1)));
  }
  #pragma unroll
  for (int off = 32; off; off >>= 1) {
    ss += __shfl_down(ss, off);
    am = fmaxf(am, __shfl_down(am, off));
  }
  __shared__ float s_ss[4], s_am[4];
  if ((tid & 63) == 0) { s_ss[tid >> 6] = ss; s_am[tid >> 6] = am; }
  __syncthreads();   // also orders: all row reads complete before in-place writes
  ss = s_ss[0] + s_ss[1] + s_ss[2] + s_ss[3];
  am = fmaxf(fmaxf(s_am[0], s_am[1]), fmaxf(s_am[2], s_am[3]));
  float rms = rsqrtf(ss * (1.0f / F) + 1e-5f);
  float a   = fmaxf(am * rms, 1e-5f);
  float qm  = rms * (127.0f / a);
  if (tid == 0) alpha[t] = a * (1.0f / 127.0f);
  uint2 w0, w1;
  w0.x = (unsigned)pack4q(blo(uu[0]), bhi(uu[0]), blo(uu[1]), bhi(uu[1]), qm);
  w0.y = (unsigned)pack4q(blo(uu[2]), bhi(uu[2]), blo(uu[3]), bhi(uu[3]), qm);
  w1.x = (unsigned)pack4q(blo(uu[4]), bhi(uu[4]), blo(uu[5]), bhi(uu[5]), qm);
  w1.y = (unsigned)pack4q(blo(uu[6]), bhi(uu[6]), blo(uu[7]), bhi(uu[7]), qm);
  *(uint2*)(rb + 8 * tid) = w0;          // i8 elems [8tid..8tid+7]
  *(uint2*)(rb + 2048 + 8 * tid) = w1;   // i8 elems [2048+8tid..]
}

// ============ i8 MFMA GEMM, 128x256 tile, 3-buffer counted-vmcnt pipeline ============
// C[m,n] = sum_k A[m,k]*B[n,k].  8 waves (2m x 4n), wave tile 64x64, BK=64.
// LDS 72 KB (3 x 24 KB) -> 2 blocks/CU.  Prefetch runs 2 tiles ahead; top-of-loop
// waits ONLY the oldest tile via vmcnt(3) (T4) -- never drains until the last tile.
// Safety: passing barrier(t) implies all waves did lgkmcnt(0) on tile t-1's frags,
// so staging into buf[(t+2)%3]==buf[(t-1)%3] after the barrier cannot race reads.
// Swizzle (both sides): 16B chunk c of row r stored at slot c^((r>>1)&3) -> conflict-free.
#define GLD16(GP, LP) __builtin_amdgcn_global_load_lds( \
    (__attribute__((address_space(1))) void*)(GP), \
    (__attribute__((address_space(3))) void*)(LP), 16, 0, 0)
#define VMCNT3 asm volatile("s_waitcnt vmcnt(3)" ::: "memory")
#define VMCNT0 asm volatile("s_waitcnt vmcnt(0)" ::: "memory")
#define LGKM0  do { asm volatile("s_waitcnt lgkmcnt(0)" ::: "memory"); __builtin_amdgcn_sched_barrier(0); } while(0)

template<int EPI>   // 0: gelu -> bf16 H    1: -> f32 Out
__global__ __launch_bounds__(512, 4) void k_gemm_i8(
    const char* __restrict__ A, int lda,          // A row stride in BYTES
    const char* __restrict__ B,                   // B packed, row stride = K bytes
    const float* __restrict__ bias, const float* __restrict__ alpha,
    const float* __restrict__ scales, int which,
    void* __restrict__ Cout, int N, int K, int lgnbx)
{
  __shared__ __align__(16) char lA[3 * 8192];    // [buf][128 rows][64 B]
  __shared__ __align__(16) char lB[3 * 16384];   // [buf][256 rows][64 B]
  const int tid = threadIdx.x, lane = tid & 63, wid = tid >> 6;
  const int wm = wid >> 2, wn = wid & 3;
  const int nwg = gridDim.x, bid = blockIdx.x;
  const int swz = (bid & 7) * (nwg >> 3) + (bid >> 3);
  const int bx = swz & ((1 << lgnbx) - 1), by = swz >> lgnbx;
  const int m0 = by * 128, n0 = bx * 256;
  const int NT = K >> 6;

  // staging: thread covers (srow, 16B slot); pre-swizzled global chunk
  const int srow = tid >> 2, slot = tid & 3;
  const int sswz = (slot ^ ((srow >> 1) & 3)) * 16;
  const char* gA0 = A + (size_t)(m0 +       srow) * lda + sswz;
  const char* gB0 = B + (size_t)(n0 +       srow) * K   + sswz;
  const char* gB1 = B + (size_t)(n0 + 128 + srow) * K   + sswz;
  const int ldst = srow * 64 + slot * 16;

  // fragment reads: lane reads k-chunk lane>>4 of its rows; phys slot applies same XOR
  const int lr = lane & 15;
  const int kx = ((lane >> 4) ^ ((lane >> 1) & 3)) * 16;
  const int aoff = (wm * 64 + lr) * 64 + kx;
  const int boff = (wn * 64 + lr) * 64 + kx;

  // prologue: tiles 0,1 -> bufs 0,1  (3 loads per tile per wave)
  GLD16(gA0,      lA + ldst);
  GLD16(gB0,      lB + ldst);
  GLD16(gB1,      lB + 8192 + ldst);
  GLD16(gA0 + 64, lA + 8192 + ldst);
  GLD16(gB0 + 64, lB + 16384 + ldst);
  GLD16(gB1 + 64, lB + 16384 + 8192 + ldst);

  i32x4 acc[4][4] = {};
  int cur = 0, nx1 = 1, nx2 = 2;
  for (int t = 0; t < NT; ++t) {
    if (t + 1 < NT) { VMCNT3; } else { VMCNT0; }  // oldest tile's 3 loads landed (per wave)
    __builtin_amdgcn_s_barrier();                 // all waves' slices landed; buf[nx2] free
    if (t + 2 < NT) {
      GLD16(gA0 + 64 * (t + 2), lA + nx2 * 8192 + ldst);
      GLD16(gB0 + 64 * (t + 2), lB + nx2 * 16384 + ldst);
      GLD16(gB1 + 64 * (t + 2), lB + nx2 * 16384 + 8192 + ldst);
    }
    i32x4 av[4], bv[4];
    {
      const char* pa = lA + cur * 8192 + aoff;
      const char* pb = lB + cur * 16384 + boff;
      #pragma unroll
      for (int j = 0; j < 4; ++j) av[j] = *(const i32x4*)(pa + j * 1024);
      #pragma unroll
      for (int n = 0; n < 4; ++n) bv[n] = *(const i32x4*)(pb + n * 1024);
    }
    LGKM0;
    __builtin_amdgcn_s_setprio(1);
    #pragma unroll
    for (int j = 0; j < 4; ++j)
      #pragma unroll
      for (int n = 0; n < 4; ++n)
        acc[j][n] = __builtin_amdgcn_mfma_i32_16x16x64_i8(av[j], bv[n], acc[j][n], 0, 0, 0);
    __builtin_amdgcn_s_setprio(0);
    int tmp = cur; cur = nx1; nx1 = nx2; nx2 = tmp;
  }

  const float wdq = scales[which];
  const int lq4 = (lane >> 4) * 4;
  #pragma unroll
  for (int m = 0; m < 4; ++m) {
    const int rowb = m0 + wm * 64 + m * 16 + lq4;
    float al[4];
    #pragma unroll
    for (int q = 0; q < 4; ++q) al[q] = alpha[rowb + q] * wdq;
    #pragma unroll
    for (int n = 0; n < 4; ++n) {
      const int col = n0 + wn * 64 + n * 16 + lr;
      const float bb = bias[col];
      #pragma unroll
      for (int q = 0; q < 4; ++q) {
        float v = (float)acc[m][n][q] * al[q] + bb;
        if constexpr (EPI == 0) {
          ((__hip_bfloat16*)Cout)[(size_t)(rowb + q) * N + col] = __float2bfloat16(fast_gelu(v));
        } else {
          ((float*)Cout)[(size_t)(rowb + q) * N + col] = v;
        }
      }
    }
  }
}

extern "C" void kernel_launch(void* const* d_in, const int* in_sizes, int n_in,
                              void* d_out, int out_size, void* d_ws, size_t ws_size,
                              hipStream_t stream) {
  const float* x  = (const float*)d_in[0];
  const float* w1 = (const float*)d_in[1];
  const float* b1 = (const float*)d_in[2];
  const float* w2 = (const float*)d_in[3];
  const float* b2 = (const float*)d_in[4];
  const int  F = in_sizes[2];                 // 4096
  const int  D = in_sizes[4];                 // 1024
  const long T = (long)in_sizes[0] / D;       // 16384 tokens
  const long nW = (long)F * D;

  char* ws = (char*)d_ws;
  float* partials = (float*)ws;               // [512] (w1: 0..255, w2: 256..511)
  float* scales   = partials + 512;           // [2]
  float* alpha1 = (float*)(ws + 4096);        // [T]
  float* alpha2 = alpha1 + T;                 // [T]
  size_t off = 4096 + 2 * (size_t)T * sizeof(float);
  off = (off + 255) & ~(size_t)255;
  char* w1q = ws + off; off += (size_t)nW;
  char* w2q = ws + off; off += (size_t)nW;
  char* xq  = ws + off; off += (size_t)T * D;
  off = (off + 255) & ~(size_t)255;
  __hip_bfloat16* h = (__hip_bfloat16*)(ws + off); off += (size_t)T * F * 2;
  if (ws_size < off) return;

  float invW = (float)(1.0 / (double)nW);
  k_reduce_abs2<<<512, 256, 0, stream>>>(w1, w2, nW / 4, partials);
  k_finalize_scales<<<1, 256, 0, stream>>>(partials, partials + 256, scales, invW, invW);
  k_quant_w2<<<4096, 256, 0, stream>>>(w1, w1q, w2, w2q, nW / 4, scales);
  k_actq_x<<<(unsigned)T, 256, 0, stream>>>(x, xq, alpha1);

  // GEMM1: [T x D] i8 @ [F x D]^T i8 -> gelu -> bf16 h
  dim3 g1((unsigned)((T / 128) * (F / 256)));  // 2048 blocks
  k_gemm_i8<0><<<g1, 512, 0, stream>>>(xq, D, w1q, b1, alpha1, scales, 0,
                                       h, F, D, __builtin_ctz(F / 256));

  // rmsnorm+quant h in place (bf16 row -> leading i8 row, stride stays F*2 bytes)
  k_actq_h<<<(unsigned)T, 256, 0, stream>>>(h, alpha2);

  // GEMM2: [T x F] i8 (stride 2F) @ [D x F]^T i8 -> f32 out
  dim3 g2((unsigned)((T / 128) * (D / 256)));  // 512 blocks
  k_gemm_i8<1><<<g2, 512, 0, stream>>>((const char*)h, F * 2, w2q, b2, alpha2, scales, 1,
                                       (float*)d_out, D, F, __builtin_ctz(D / 256));
}